// Round 2
// baseline (992.686 us; speedup 1.0000x reference)
//
#include <hip/hip_runtime.h>
#include <hip/hip_bf16.h>
#include <math.h>

typedef unsigned short u16;
typedef unsigned int u32;
typedef short s8v __attribute__((ext_vector_type(8)));
typedef float f4v __attribute__((ext_vector_type(4)));

#define D_MODEL 1024
#define D_FF    4096
#define NE      24
#define T_TOT   2048
#define SLOTS   (2*T_TOT)
#define CAP     2048
#define BM      64
#define BN      128
#define BK      32
#define MAXT    96
#define LDA     40   // padded LDS row stride in bf16 elems (80B: 16B-aligned, 2-way banks = free)

// ---- ws layout (bytes) ----
#define OFF_GATES   0                          // float [2048][2]
#define OFF_COUNTS  (OFF_GATES + T_TOT*2*4)    // int[24], padded
#define OFF_NT      (OFF_COUNTS + 128)         // int[1]
#define OFF_MT      (OFF_NT + 128)             // int[128]
#define OFF_TLIST   (OFF_MT + 512)             // int[24][2048]
#define OFF_H       (OFF_TLIST + NE*CAP*4)     // bf16 [SLOTS][D_FF]
#define OFF_Y       (OFF_H + (size_t)SLOTS*D_FF*2) // float [SLOTS][D_MODEL]  (~50.6 MB total)

__device__ __forceinline__ u16 f2bf(float f) {
    u32 u = __builtin_bit_cast(u32, f);
    u32 r = (u + 0x7FFF + ((u >> 16) & 1)) >> 16;   // RNE
    return (u16)r;
}
__device__ __forceinline__ float bf2f(u16 u) {
    u32 x = ((u32)u) << 16;
    return __builtin_bit_cast(float, x);
}

// ---------------- kernel 0: zero expert counts ----------------
__global__ void zero_kern(int* __restrict__ counts) {
    if (threadIdx.x < NE) counts[threadIdx.x] = 0;
}

// ---------------- kernel 1: gating (fp32 scores -> top2 -> softmax -> lists) ----------------
// one wave (64 threads) per token
__global__ void gate_kern(const float* __restrict__ x, const float* __restrict__ gw,
                          const float* __restrict__ gb, float* __restrict__ gates,
                          int* __restrict__ counts, int* __restrict__ tlist) {
    int t = blockIdx.x;
    int lane = threadIdx.x;
    float acc[NE];
#pragma unroll
    for (int e = 0; e < NE; e++) acc[e] = 0.f;
    const float* xr = x + (size_t)t * D_MODEL;
#pragma unroll 4
    for (int i = 0; i < D_MODEL / 64; i++) {
        int d = lane + i * 64;
        float xv = xr[d];
        const float* g = gw + (size_t)d * NE;
#pragma unroll
        for (int e = 0; e < NE; e++) acc[e] = fmaf(xv, g[e], acc[e]);
    }
#pragma unroll
    for (int m = 1; m < 64; m <<= 1) {
#pragma unroll
        for (int e = 0; e < NE; e++) acc[e] += __shfl_xor(acc[e], m, 64);
    }
    if (lane == 0) {
        float v0 = -1e30f, v1 = -1e30f;
        int i0 = 0, i1 = 0;
#pragma unroll
        for (int e = 0; e < NE; e++) {
            float v = acc[e] + gb[e];
            if (v > v0) { v1 = v0; i1 = i0; v0 = v; i0 = e; }
            else if (v > v1) { v1 = v; i1 = e; }
        }
        float e1 = __expf(v1 - v0);
        float inv = 1.f / (1.f + e1);
        gates[t * 2 + 0] = inv;
        gates[t * 2 + 1] = e1 * inv;
        int p0 = atomicAdd(&counts[i0], 1);
        tlist[i0 * CAP + p0] = t * 2 + 0;
        int p1 = atomicAdd(&counts[i1], 1);
        tlist[i1 * CAP + p1] = t * 2 + 1;
    }
}

// ---------------- kernel 2: schedule (pad lists, build m-tile worklist) ----------------
__global__ void sched_kern(const int* __restrict__ counts, int* __restrict__ ntl,
                           int* __restrict__ mtl, int* __restrict__ tlist) {
    int tid = threadIdx.x;
    for (int idx = tid; idx < NE * 64; idx += 256) {
        int e = idx >> 6, j = idx & 63;
        int c = counts[e];
        int cr = ((c + BM - 1) / BM) * BM;
        if (c + j < cr) tlist[e * CAP + c + j] = -1;
    }
    if (tid == 0) {
        int tot = 0;
        for (int e = 0; e < NE; e++) {
            int nt = (counts[e] + BM - 1) / BM;
            for (int i = 0; i < nt; i++) mtl[tot++] = (e << 16) | i;
        }
        ntl[0] = tot;
    }
}

// ---------------- kernel 3: grouped GEMM1  h = gelu(x @ w1 + b1), fp32 in, bf16 out ----------------
__global__ __launch_bounds__(256) void gemm1_kern(
    const float* __restrict__ x, const float* __restrict__ w1, const float* __restrict__ b1,
    const int* __restrict__ ntl, const int* __restrict__ mtl, const int* __restrict__ tlist,
    u16* __restrict__ h) {
    int mt = blockIdx.y;
    if (mt >= ntl[0]) return;
    int ent = mtl[mt];
    int e = ent >> 16, tile = ent & 0xFFFF;
    int f0 = blockIdx.x * BN;
    const int* tl = tlist + e * CAP + tile * BM;

    __shared__ u16 As[BM * LDA];
    __shared__ u16 Bs[BN * LDA];

    int tid = threadIdx.x;
    // A staging: thread -> (row, 8-k chunk)
    int arow = tid >> 2, akc = (tid & 3) * 8;
    int aslot = tl[arow];
    const float* ap = x + (size_t)(aslot >> 1) * D_MODEL + akc;
    // B staging: thread -> (4 n cols, 4 k rows); fp32->bf16 + transpose in registers
    int bn4 = (tid & 31) * 4, bkb = (tid >> 5) * 4;
    const float* bp = w1 + (size_t)e * D_MODEL * D_FF + f0 + bn4;

    int wave = tid >> 6, lane = tid & 63;
    int quad = lane >> 4, l16 = lane & 15;

    f4v acc[4][2];
#pragma unroll
    for (int i = 0; i < 4; i++)
#pragma unroll
        for (int j = 0; j < 2; j++) acc[i][j] = (f4v){0.f, 0.f, 0.f, 0.f};

    for (int k0 = 0; k0 < D_MODEL; k0 += BK) {
        ushort4 av0 = {0, 0, 0, 0}, av1 = {0, 0, 0, 0};
        if (aslot >= 0) {
            float4 a0 = *(const float4*)(ap + k0);
            float4 a1 = *(const float4*)(ap + k0 + 4);
            av0 = (ushort4){f2bf(a0.x), f2bf(a0.y), f2bf(a0.z), f2bf(a0.w)};
            av1 = (ushort4){f2bf(a1.x), f2bf(a1.y), f2bf(a1.z), f2bf(a1.w)};
        }
        *(ushort4*)&As[arow * LDA + akc] = av0;
        *(ushort4*)&As[arow * LDA + akc + 4] = av1;

        float4 q0 = *(const float4*)(bp + (size_t)(k0 + bkb + 0) * D_FF);
        float4 q1 = *(const float4*)(bp + (size_t)(k0 + bkb + 1) * D_FF);
        float4 q2 = *(const float4*)(bp + (size_t)(k0 + bkb + 2) * D_FF);
        float4 q3 = *(const float4*)(bp + (size_t)(k0 + bkb + 3) * D_FF);
        const float* p0 = (const float*)&q0;
        const float* p1 = (const float*)&q1;
        const float* p2 = (const float*)&q2;
        const float* p3 = (const float*)&q3;
#pragma unroll
        for (int j = 0; j < 4; j++) {
            uint2 wv;
            wv.x = (u32)f2bf(p0[j]) | ((u32)f2bf(p1[j]) << 16);
            wv.y = (u32)f2bf(p2[j]) | ((u32)f2bf(p3[j]) << 16);
            *(uint2*)&Bs[(bn4 + j) * LDA + bkb] = wv;
        }
        __syncthreads();

        s8v af[4], bfr[2];
#pragma unroll
        for (int mf = 0; mf < 4; mf++)
            af[mf] = *(const s8v*)&As[(mf * 16 + l16) * LDA + quad * 8];
#pragma unroll
        for (int nf = 0; nf < 2; nf++)
            bfr[nf] = *(const s8v*)&Bs[(wave * 32 + nf * 16 + l16) * LDA + quad * 8];
#pragma unroll
        for (int mf = 0; mf < 4; mf++)
#pragma unroll
            for (int nf = 0; nf < 2; nf++)
                acc[mf][nf] = __builtin_amdgcn_mfma_f32_16x16x32_bf16(af[mf], bfr[nf], acc[mf][nf], 0, 0, 0);
        __syncthreads();
    }

    // epilogue: bias + exact gelu -> bf16 h[slot][f]
#pragma unroll
    for (int mf = 0; mf < 4; mf++) {
        int rowb = mf * 16 + quad * 4;
#pragma unroll
        for (int r = 0; r < 4; r++) {
            int slot = tl[rowb + r];
            if (slot < 0) continue;
#pragma unroll
            for (int nf = 0; nf < 2; nf++) {
                int f = f0 + wave * 32 + nf * 16 + l16;
                float v = acc[mf][nf][r] + b1[e * D_FF + f];
                float g = 0.5f * v * (1.f + erff(v * 0.70710678118654752f));
                h[(size_t)slot * D_FF + f] = f2bf(g);
            }
        }
    }
}

// ---------------- kernel 4: grouped GEMM2  y = h @ w2 + b2, h bf16, w2 fp32, y fp32 ----------------
__global__ __launch_bounds__(256) void gemm2_kern(
    const u16* __restrict__ h, const float* __restrict__ w2, const float* __restrict__ b2,
    const int* __restrict__ ntl, const int* __restrict__ mtl, const int* __restrict__ tlist,
    float* __restrict__ y) {
    int mt = blockIdx.y;
    if (mt >= ntl[0]) return;
    int ent = mtl[mt];
    int e = ent >> 16, tile = ent & 0xFFFF;
    int d0 = blockIdx.x * BN;
    const int* tl = tlist + e * CAP + tile * BM;

    __shared__ u16 As[BM * LDA];
    __shared__ u16 Bs[BN * LDA];

    int tid = threadIdx.x;
    int arow = tid >> 2, akc = (tid & 3) * 8;
    int aslot = tl[arow];
    const u16* ap = h + (size_t)aslot * D_FF + akc;
    int bn4 = (tid & 31) * 4, bkb = (tid >> 5) * 4;
    const float* bp = w2 + (size_t)e * D_FF * D_MODEL + d0 + bn4;

    int wave = tid >> 6, lane = tid & 63;
    int quad = lane >> 4, l16 = lane & 15;

    f4v acc[4][2];
#pragma unroll
    for (int i = 0; i < 4; i++)
#pragma unroll
        for (int j = 0; j < 2; j++) acc[i][j] = (f4v){0.f, 0.f, 0.f, 0.f};

    for (int k0 = 0; k0 < D_FF; k0 += BK) {
        uint4 av = {0u, 0u, 0u, 0u};
        if (aslot >= 0) av = *(const uint4*)(ap + k0);   // h already bf16
        *(uint4*)&As[arow * LDA + akc] = av;

        float4 q0 = *(const float4*)(bp + (size_t)(k0 + bkb + 0) * D_MODEL);
        float4 q1 = *(const float4*)(bp + (size_t)(k0 + bkb + 1) * D_MODEL);
        float4 q2 = *(const float4*)(bp + (size_t)(k0 + bkb + 2) * D_MODEL);
        float4 q3 = *(const float4*)(bp + (size_t)(k0 + bkb + 3) * D_MODEL);
        const float* p0 = (const float*)&q0;
        const float* p1 = (const float*)&q1;
        const float* p2 = (const float*)&q2;
        const float* p3 = (const float*)&q3;
#pragma unroll
        for (int j = 0; j < 4; j++) {
            uint2 wv;
            wv.x = (u32)f2bf(p0[j]) | ((u32)f2bf(p1[j]) << 16);
            wv.y = (u32)f2bf(p2[j]) | ((u32)f2bf(p3[j]) << 16);
            *(uint2*)&Bs[(bn4 + j) * LDA + bkb] = wv;
        }
        __syncthreads();

        s8v af[4], bfr[2];
#pragma unroll
        for (int mf = 0; mf < 4; mf++)
            af[mf] = *(const s8v*)&As[(mf * 16 + l16) * LDA + quad * 8];
#pragma unroll
        for (int nf = 0; nf < 2; nf++)
            bfr[nf] = *(const s8v*)&Bs[(wave * 32 + nf * 16 + l16) * LDA + quad * 8];
#pragma unroll
        for (int mf = 0; mf < 4; mf++)
#pragma unroll
            for (int nf = 0; nf < 2; nf++)
                acc[mf][nf] = __builtin_amdgcn_mfma_f32_16x16x32_bf16(af[mf], bfr[nf], acc[mf][nf], 0, 0, 0);
        __syncthreads();
    }

#pragma unroll
    for (int mf = 0; mf < 4; mf++) {
        int rowb = mf * 16 + quad * 4;
#pragma unroll
        for (int r = 0; r < 4; r++) {
            int slot = tl[rowb + r];
            if (slot < 0) continue;
#pragma unroll
            for (int nf = 0; nf < 2; nf++) {
                int d = d0 + wave * 32 + nf * 16 + l16;
                y[(size_t)slot * D_MODEL + d] = acc[mf][nf][r] + b2[e * D_MODEL + d];
            }
        }
    }
}

// ---------------- kernel 5: combine  out = x + g0*y[2t] + g1*y[2t+1], all fp32 ----------------
__global__ void combine_kern(const float* __restrict__ x, const float* __restrict__ y,
                             const float* __restrict__ gates, float* __restrict__ out) {
    int gid = blockIdx.x * blockDim.x + threadIdx.x;
    int t = gid >> 7;              // 128 chunks of 8 floats per token
    int c = (gid & 127) << 3;
    float g0 = gates[t * 2 + 0], g1 = gates[t * 2 + 1];
    const float* xp = x + (size_t)t * D_MODEL + c;
    const float* ap = y + (size_t)(t * 2 + 0) * D_MODEL + c;
    const float* bp = y + (size_t)(t * 2 + 1) * D_MODEL + c;
    float* op = out + (size_t)t * D_MODEL + c;
    float4 x0 = *(const float4*)(xp), x1 = *(const float4*)(xp + 4);
    float4 a0 = *(const float4*)(ap), a1 = *(const float4*)(ap + 4);
    float4 b0 = *(const float4*)(bp), b1v = *(const float4*)(bp + 4);
    float4 o0, o1;
    o0.x = x0.x + g0 * a0.x + g1 * b0.x;
    o0.y = x0.y + g0 * a0.y + g1 * b0.y;
    o0.z = x0.z + g0 * a0.z + g1 * b0.z;
    o0.w = x0.w + g0 * a0.w + g1 * b0.w;
    o1.x = x1.x + g0 * a1.x + g1 * b1v.x;
    o1.y = x1.y + g0 * a1.y + g1 * b1v.y;
    o1.z = x1.z + g0 * a1.z + g1 * b1v.z;
    o1.w = x1.w + g0 * a1.w + g1 * b1v.w;
    *(float4*)(op) = o0;
    *(float4*)(op + 4) = o1;
}

extern "C" void kernel_launch(void* const* d_in, const int* in_sizes, int n_in,
                              void* d_out, int out_size, void* d_ws, size_t ws_size,
                              hipStream_t stream) {
    const float* x  = (const float*)d_in[0];
    const float* gw = (const float*)d_in[1];
    const float* gb = (const float*)d_in[2];
    const float* w1 = (const float*)d_in[3];
    const float* b1 = (const float*)d_in[4];
    const float* w2 = (const float*)d_in[5];
    const float* b2 = (const float*)d_in[6];
    float* out = (float*)d_out;

    char* ws = (char*)d_ws;
    float* gates = (float*)(ws + OFF_GATES);
    int* counts  = (int*)(ws + OFF_COUNTS);
    int* ntl     = (int*)(ws + OFF_NT);
    int* mtl     = (int*)(ws + OFF_MT);
    int* tlist   = (int*)(ws + OFF_TLIST);
    u16* h       = (u16*)(ws + OFF_H);
    float* y     = (float*)(ws + OFF_Y);

    zero_kern<<<1, 64, 0, stream>>>(counts);
    gate_kern<<<T_TOT, 64, 0, stream>>>(x, gw, gb, gates, counts, tlist);
    sched_kern<<<1, 256, 0, stream>>>(counts, ntl, mtl, tlist);
    gemm1_kern<<<dim3(D_FF / BN, MAXT), 256, 0, stream>>>(x, w1, b1, ntl, mtl, tlist, h);
    gemm2_kern<<<dim3(D_MODEL / BN, MAXT), 256, 0, stream>>>(h, w2, b2, ntl, mtl, tlist, y);
    combine_kern<<<(T_TOT * D_MODEL / 8) / 256, 256, 0, stream>>>(x, y, gates, out);
}